// Round 2
// baseline (359.046 us; speedup 1.0000x reference)
//
#include <hip/hip_runtime.h>

// MeanPooling: B=64 segments, L=2048 tokens, D=512 fp32 features.
// out[0 : 64*512]          = per-segment mean
// out[64*512 : +131072]    = attn weights (1/len per token)
//
// Memory-bound: 256 MiB read once, ~0.64 MiB written. HBM floor ~43 us.
// Single dispatch: grid = 64 segments x 8 feature-slices. Each block owns a
// 64-float (16 x float4) feature slice over all 2048 tokens of its segment,
// reduces 32 token-phases in LDS, writes the mean slice directly.
// No atomics, no zero-init, no workspace.

#define SEG_B   64
#define SEG_L   2048
#define DIM     512
#define F4      (DIM / 4)      // 128 float4 per row
#define NSLICE  8
#define SLICE_F4 16            // float4 per slice (64 floats)
#define BLOCK   512
#define NPH     (BLOCK / SLICE_F4)   // 32 token phases; each thread sums 64 tokens

__global__ __launch_bounds__(BLOCK)
void MeanPooling_40845138985511_kernel(const float* __restrict__ x,
                                       const int* __restrict__ lengths,
                                       float* __restrict__ out,    // [B*D]
                                       float* __restrict__ attn) { // [N]
    const int b   = blockIdx.x >> 3;       // segment
    const int sl  = blockIdx.x & (NSLICE - 1);
    const int tid = threadIdx.x;
    const int fg  = tid & (SLICE_F4 - 1);  // float4 within slice
    const int ph  = tid >> 4;              // token phase [0,32)

    const float inv = 1.0f / (float)lengths[b];

    // Wave = fg 0..15 x 4 consecutive phases -> 4 x 256B contiguous chunks/load.
    const float4* xp = (const float4*)x
                     + (size_t)b * SEG_L * F4 + sl * SLICE_F4 + fg;

    float4 acc = make_float4(0.f, 0.f, 0.f, 0.f);
#pragma unroll 8
    for (int t = ph; t < SEG_L; t += NPH) {
        float4 v = xp[(size_t)t * F4];
        acc.x += v.x; acc.y += v.y; acc.z += v.z; acc.w += v.w;
    }

    // LDS tree-reduce over the 32 phases (layout: [ph][fg], stride 16).
    __shared__ float4 sm[BLOCK];
    sm[tid] = acc;
    __syncthreads();
#pragma unroll
    for (int s = BLOCK / 2; s >= SLICE_F4; s >>= 1) {
        if (tid < s) {
            float4 o = sm[tid + s];
            float4 m = sm[tid];
            m.x += o.x; m.y += o.y; m.z += o.z; m.w += o.w;
            sm[tid] = m;
        }
        __syncthreads();
    }

    if (tid < SLICE_F4) {
        float4 r = sm[tid];
        r.x *= inv; r.y *= inv; r.z *= inv; r.w *= inv;
        ((float4*)(out + (size_t)b * DIM + sl * (SLICE_F4 * 4)))[tid] = r;
    }

    // Attention weights: this block covers 256 of its segment's tokens.
    if (tid < SEG_L / NSLICE) {  // 256 threads
        attn[(size_t)b * SEG_L + sl * (SEG_L / NSLICE) + tid] = inv;
    }
}

extern "C" void kernel_launch(void* const* d_in, const int* in_sizes, int n_in,
                              void* d_out, int out_size, void* d_ws, size_t ws_size,
                              hipStream_t stream) {
    const float* x       = (const float*)d_in[0];
    const int*   lengths = (const int*)d_in[1];
    float* out  = (float*)d_out;
    float* attn = out + SEG_B * DIM;

    MeanPooling_40845138985511_kernel<<<SEG_B * NSLICE, BLOCK, 0, stream>>>(
        x, lengths, out, attn);
}